// Round 4
// baseline (309.268 us; speedup 1.0000x reference)
//
#include <hip/hip_runtime.h>
#include <math.h>

typedef unsigned short u16;
typedef unsigned int   u32;

#define S2 0.70710678118654752440f

typedef float f32x4 __attribute__((ext_vector_type(4)));
typedef short bf16x8 __attribute__((ext_vector_type(8)));
typedef float f32x2 __attribute__((ext_vector_type(2)));
typedef __bf16 bf16x2 __attribute__((ext_vector_type(2)));
#define MFMA(a,b,c) __builtin_amdgcn_mfma_f32_16x16x32_bf16(a,b,c,0,0,0)

__device__ __forceinline__ float bf2f(u16 u){
  union { u32 i; float f; } v; v.i = ((u32)u) << 16; return v.f;
}
// native scalar f32 -> bf16 (RNE), 1 VALU op on gfx950
__device__ __forceinline__ u16 f2bf(float f){
  union { __bf16 b; u16 u; } v; v.b = (__bf16)f; return v.u;
}
// native packed f32x2 -> bf16x2 (RNE) via fptrunc <2 x float>, selects v_cvt_pk_bf16_f32
__device__ __forceinline__ u32 pk_bf16(float lo, float hi){
  f32x2 s; s.x = lo; s.y = hi;
  union { bf16x2 h; u32 u; } v;
  v.h = __builtin_convertvector(s, bf16x2);
  return v.u;
}

struct C2 { float r, i; };

__device__ __forceinline__ void fft8_fwd(C2* y){
  C2 a0 = {y[0].r+y[4].r, y[0].i+y[4].i};
  C2 a1 = {y[0].r-y[4].r, y[0].i-y[4].i};
  C2 a2 = {y[2].r+y[6].r, y[2].i+y[6].i};
  C2 a3 = {y[2].r-y[6].r, y[2].i-y[6].i};
  C2 b0 = {y[1].r+y[5].r, y[1].i+y[5].i};
  C2 b1 = {y[1].r-y[5].r, y[1].i-y[5].i};
  C2 b2 = {y[3].r+y[7].r, y[3].i+y[7].i};
  C2 b3 = {y[3].r-y[7].r, y[3].i-y[7].i};
  C2 E0 = {a0.r+a2.r, a0.i+a2.i};
  C2 E2 = {a0.r-a2.r, a0.i-a2.i};
  C2 E1 = {a1.r+a3.i, a1.i-a3.r};
  C2 E3 = {a1.r-a3.i, a1.i+a3.r};
  C2 O0 = {b0.r+b2.r, b0.i+b2.i};
  C2 O2 = {b0.r-b2.r, b0.i-b2.i};
  C2 O1 = {b1.r+b3.i, b1.i-b3.r};
  C2 O3 = {b1.r-b3.i, b1.i+b3.r};
  C2 t1 = {S2*(O1.r+O1.i), S2*(O1.i-O1.r)};
  C2 t2 = {O2.i, -O2.r};
  C2 t3 = {S2*(O3.i-O3.r), -S2*(O3.r+O3.i)};
  y[0].r=E0.r+O0.r; y[0].i=E0.i+O0.i;
  y[4].r=E0.r-O0.r; y[4].i=E0.i-O0.i;
  y[1].r=E1.r+t1.r; y[1].i=E1.i+t1.i;
  y[5].r=E1.r-t1.r; y[5].i=E1.i-t1.i;
  y[2].r=E2.r+t2.r; y[2].i=E2.i+t2.i;
  y[6].r=E2.r-t2.r; y[6].i=E2.i-t2.i;
  y[3].r=E3.r+t3.r; y[3].i=E3.i+t3.i;
  y[7].r=E3.r-t3.r; y[7].i=E3.i-t3.i;
}

__device__ __forceinline__ void fft8_inv(C2* z){
  C2 A0 = {z[0].r+z[4].r, z[0].i+z[4].i};
  C2 A1 = {z[1].r+z[5].r, z[1].i+z[5].i};
  C2 A2 = {z[2].r+z[6].r, z[2].i+z[6].i};
  C2 A3 = {z[3].r+z[7].r, z[3].i+z[7].i};
  C2 D0 = {z[0].r-z[4].r, z[0].i-z[4].i};
  C2 D1 = {z[1].r-z[5].r, z[1].i-z[5].i};
  C2 D2 = {z[2].r-z[6].r, z[2].i-z[6].i};
  C2 D3 = {z[3].r-z[7].r, z[3].i-z[7].i};
  C2 B0 = D0;
  C2 B1 = {S2*(D1.r-D1.i), S2*(D1.i+D1.r)};
  C2 B2 = {-D2.i, D2.r};
  C2 B3 = {-S2*(D3.r+D3.i), S2*(D3.r-D3.i)};
  z[0].r = A0.r+A1.r+A2.r+A3.r;           z[0].i = A0.i+A1.i+A2.i+A3.i;
  z[2].r = A0.r-A2.r-(A1.i-A3.i);         z[2].i = A0.i-A2.i+(A1.r-A3.r);
  z[4].r = A0.r-A1.r+A2.r-A3.r;           z[4].i = A0.i-A1.i+A2.i-A3.i;
  z[6].r = A0.r-A2.r+(A1.i-A3.i);         z[6].i = A0.i-A2.i-(A1.r-A3.r);
  z[1].r = B0.r+B1.r+B2.r+B3.r;           z[1].i = B0.i+B1.i+B2.i+B3.i;
  z[3].r = B0.r-B2.r-(B1.i-B3.i);         z[3].i = B0.i-B2.i+(B1.r-B3.r);
  z[5].r = B0.r-B1.r+B2.r-B3.r;           z[5].i = B0.i-B1.i+B2.i-B3.i;
  z[7].r = B0.r-B2.r+(B1.i-B3.i);         z[7].i = B0.i-B2.i-(B1.r-B3.r);
}

__device__ __forceinline__ void rfft8_row(float* x){
  float et0=x[0]+x[4], et1=x[0]-x[4], et2=x[2]+x[6], et3=x[2]-x[6];
  float ot0=x[1]+x[5], ot1=x[1]-x[5], ot2=x[3]+x[7], ot3=x[3]-x[7];
  float E0=et0+et2, E2=et0-et2;
  float O0=ot0+ot2, O2=ot0-ot2;
  float om=S2*(ot1-ot3), op=S2*(ot1+ot3);
  x[0]=E0+O0;  x[1]=E0-O0;
  x[2]=et1+om; x[3]=-et3-op;
  x[4]=E2;     x[5]=-O2;
  x[6]=et1-om; x[7]=et3-op;
}

__device__ __forceinline__ void irfft8_row(float f0, C2 R1, C2 R2, C2 R3, float f4, float* x){
  float A0  = f0+f4, B0v = f0-f4;
  float A1r = R1.r+R3.r, A1i = R1.i-R3.i;
  float A2  = 2.f*R2.r;
  float D1r = R1.r-R3.r, D1i = R1.i+R3.i;
  float B1r = S2*(D1r-D1i), B1i = S2*(D1i+D1r);
  float B2  = -2.f*R2.i;
  const float k = 1.f/64.f;
  x[0]=k*(A0 +A2+2.f*A1r); x[2]=k*(A0 -A2-2.f*A1i);
  x[4]=k*(A0 +A2-2.f*A1r); x[6]=k*(A0 -A2+2.f*A1i);
  x[1]=k*(B0v+B2+2.f*B1r); x[3]=k*(B0v-B2-2.f*B1i);
  x[5]=k*(B0v+B2-2.f*B1r); x[7]=k*(B0v-B2+2.f*B1i);
}

// ---------------- K_prep: fp32 weights -> bf16 ----------------
__global__ void k_prep(const float* __restrict__ wi, const float* __restrict__ we,
                       const float* __restrict__ wo,
                       u16* __restrict__ wbi, u16* __restrict__ wbe, u16* __restrict__ wbo){
  int i = blockIdx.x*256 + threadIdx.x;   // 20480
  if (i < 8192)        wbi[i]        = f2bf(wi[i]);
  else if (i < 16384)  wbe[i-8192]   = f2bf(we[i-8192]);
  else if (i < 20480)  wbo[i-16384]  = f2bf(wo[i-16384]);
}

// ---------------- K_front: 1x1 convs (MFMA) + patch FFT ----------------
// block = 2 horizontal patches (128 pixels), 256 threads
// y layout (bf16): [b][ph(32)][pw(32)][k=r*8+col (64)][c' (128)] where
// c' = (c&31)|((c&32)<<1)|((c&64)>>1)  (chunk-contiguous permutation for k_back)
// LDS = single 32 KB buffer: the 16 KB A-staging region aliases the low half of
// s_spec (never simultaneously live; enforced by the barrier inside do_gemm
// between A-fragment ds_reads and the epilogue overwrite, and the barrier
// between read_spec(pe) and do_stage(img)). 48->32 KB raises LDS block cap 3->5.
__global__ __launch_bounds__(256, 2)
void k_front(const float* __restrict__ img, const float* __restrict__ evt,
             const u16* __restrict__ wbi, const u16* __restrict__ wbe,
             const float* __restrict__ filt, u16* __restrict__ yout){
  __shared__ __align__(16) u16 s_spec[16384];  // 32 KB  [och(128)][pix(128)] swizzled / stage
  u16* const s_a = s_spec;                     // alias: [pix(128)][c(64)] xor-swizzled (16 KB)

  const int t   = threadIdx.x;
  const int bid = blockIdx.x;          // 2048 = b(4) * ph(32) * bx(16)
  const int b   = bid >> 9;
  const int ph  = (bid >> 4) & 31;
  const int bx  = bid & 15;
  const int wv   = t >> 6;
  const int quad = (t >> 4) & 3;
  const int ln15 = t & 15;
  const int pc   = t >> 7;             // fft patch (0/1)
  const int c    = t & 127;            // fft channel (original index)

  auto do_stage = [&](const float* src){
    #pragma unroll
    for (int i=0;i<8;i++){
      int task = t + 256*i;
      int ci = task>>5, q = task&31;
      int r = q>>2, j = q&3;
      const float4 v = *(const float4*)(src +
          (((size_t)(b*64+ci)*256 + ph*8 + r)*256 + bx*16 + j*4));
      int p0 = (j>>1)*64 + r*8 + (j&1)*4;
      int gbase = ci>>3, cl = ci&7;
      float vv[4] = {v.x, v.y, v.z, v.w};
      #pragma unroll
      for (int w=0;w<4;w++){
        int p = p0+w;
        int g = gbase ^ (p&7) ^ r;
        s_a[p*64 + g*8 + cl] = f2bf(vv[w]);
      }
    }
  };

  auto do_gemm = [&](const u16* __restrict__ wb){
    f32x4 acc[2][8];
    #pragma unroll
    for (int nt=0;nt<2;nt++)
      #pragma unroll
      for (int mt=0;mt<8;mt++)
        acc[nt][mt] = (f32x4){0.f,0.f,0.f,0.f};
    const int nb = wv*32;
    #pragma unroll
    for (int kk=0;kk<2;kk++){
      bf16x8 bf0 = *(const bf16x8*)&wb[(nb      + ln15)*64 + kk*32 + quad*8];
      bf16x8 bf1 = *(const bf16x8*)&wb[(nb + 16 + ln15)*64 + kk*32 + quad*8];
      #pragma unroll
      for (int mt=0;mt<8;mt++){
        int pix = mt*16 + ln15;
        int g = (kk*4+quad) ^ (pix&7) ^ ((pix>>3)&7);
        bf16x8 af = *(const bf16x8*)&s_a[pix*64 + g*8];
        acc[0][mt] = MFMA(af, bf0, acc[0][mt]);
        acc[1][mt] = MFMA(af, bf1, acc[1][mt]);
      }
    }
    // all A-fragment reads (staging region) must complete in every wave
    // before the epilogue overwrites the aliased buffer
    __syncthreads();
    #pragma unroll
    for (int nt=0;nt<2;nt++){
      int och = nb + nt*16 + ln15;
      #pragma unroll
      for (int mt=0;mt<8;mt++){
        int p0 = mt*16 + quad*4;
        f32x4 v = acc[nt][mt];
        u32 lo = pk_bf16(v.x, v.y);
        u32 hi = pk_bf16(v.z, v.w);
        int d = (p0>>3) ^ (och&7);
        u32* dst = (u32*)&s_spec[och*128 + d*8 + (p0&7)];
        dst[0] = lo; dst[1] = hi;
      }
    }
  };

  auto read_spec = [&](float* p){
    #pragma unroll
    for (int d=0; d<8; d++){
      int cz = (pc*8+d) ^ (c&7);
      const uint4 q4 = *(const uint4*)&s_spec[c*128 + cz*8];
      u32 ws4[4] = {q4.x, q4.y, q4.z, q4.w};
      #pragma unroll
      for (int e=0;e<4;e++){
        p[d*8+2*e]   = bf2f((u16)(ws4[e] & 0xFFFFu));
        p[d*8+2*e+1] = bf2f((u16)(ws4[e] >> 16));
      }
    }
  };

  // ---- event: stage -> GEMM -> row spectra ----
  do_stage(evt);
  __syncthreads();
  do_gemm(wbe);
  __syncthreads();

  float pe[64];
  read_spec(pe);
  #pragma unroll
  for (int r=0;r<8;r++) rfft8_row(&pe[r*8]);
  __syncthreads();          // pe spectra reads done; staging region free for img

  // ---- img: stage -> GEMM ----
  do_stage(img);
  __syncthreads();
  do_gemm(wbi);
  __syncthreads();

  // ---- FFT2: merged columns, X = (Fi+1)*(Fe*f) ----
  float pi[64];
  read_spec(pi);
  __syncthreads();          // all s_spec reads done; safe to overwrite below
  #pragma unroll
  for (int r=0;r<8;r++) rfft8_row(&pi[r*8]);

  C2 X[8][5];
  {
    const float* fl = filt + c*40;
    #pragma unroll
    for (int j=0;j<5;j++){
      C2 e8[8], i8[8];
      #pragma unroll
      for (int r=0;r<8;r++){
        float re_e, im_e, re_i, im_i;
        if (j==0){ re_e=pe[r*8];   im_e=0.f; re_i=pi[r*8];   im_i=0.f; }
        else if (j==4){ re_e=pe[r*8+1]; im_e=0.f; re_i=pi[r*8+1]; im_i=0.f; }
        else { re_e=pe[r*8+2*j]; im_e=pe[r*8+2*j+1];
               re_i=pi[r*8+2*j]; im_i=pi[r*8+2*j+1]; }
        e8[r].r=re_e; e8[r].i=im_e; i8[r].r=re_i; i8[r].i=im_i;
      }
      fft8_fwd(e8);
      fft8_fwd(i8);
      #pragma unroll
      for (int ky=0;ky<8;ky++){
        float f  = fl[ky*5+j];
        float fr = e8[ky].r*f, fi2 = e8[ky].i*f;
        X[ky][j].r = i8[ky].r*fr - i8[ky].i*fi2 + fr;
        X[ky][j].i = i8[ky].r*fi2 + i8[ky].i*fr + fi2;
      }
    }
    #pragma unroll
    for (int j=0;j<5;j++){
      C2 z[8];
      #pragma unroll
      for (int ky=0;ky<8;ky++) z[ky] = X[ky][j];
      fft8_inv(z);
      #pragma unroll
      for (int ky=0;ky<8;ky++) X[ky][j] = z[ky];
    }
  }

  // row irffts -> stage writes (channel-permuted)
  {
    const int cp = (c&31) | ((c&32)<<1) | ((c&64)>>1);
    #pragma unroll
    for (int r=0;r<8;r++){
      float xr[8];
      irfft8_row(X[r][0].r, X[r][1], X[r][2], X[r][3], X[r][4].r, xr);
      #pragma unroll
      for (int n2=0;n2<8;n2++)
        s_spec[(pc*64 + r*8 + n2)*128 + cp] = f2bf(xr[n2]);
    }
  }
  __syncthreads();

  // ---- coalesced store (32 KB) ----
  {
    const uint4* sg = (const uint4*)s_spec;
    uint4* dst = (uint4*)(yout + (size_t)(b*1024 + ph*32 + bx*2)*8192);
    #pragma unroll
    for (int i=0;i<8;i++){
      int q2 = t + 256*i;
      dst[q2] = sg[q2];
    }
  }
}

// ---------------- K_back: dw3x3 + gelu-gate + 1x1 out (MFMA) ----------------
// block = 16x16 pixel tile, 256 threads. Reads permuted y: chunk ch = 128 B contiguous.
__global__ __launch_bounds__(256, 2)
void k_back(const u16* __restrict__ y, const float* __restrict__ wdw,
            const u16* __restrict__ wbo, float* __restrict__ out){
  __shared__ __align__(16) u16 L[18*19*68];   // 46512 B: [py 18][px 19][ch 64 +4 pad]
  __shared__ __align__(16) u16 A[256*32];     // 16384 B: [pix 256][ch 32] xor-swizzled

  const int t   = threadIdx.x;
  const int bid = blockIdx.x;     // 1024 = b(4) * ty(16) * tx(16)
  const int b   = bid >> 8;
  const int ty  = (bid >> 4) & 15;
  const int tx  = bid & 15;
  const int wv   = t >> 6;
  const int quad = (t >> 4) & 3;
  const int ln15 = t & 15;
  const int y_  = t >> 4, x_ = t & 15;
  const int sw  = (t&3) ^ ((t>>2)&3);

  f32x4 acc[4][4];
  #pragma unroll
  for (int mt=0;mt<4;mt++)
    #pragma unroll
    for (int nt=0;nt<4;nt++)
      acc[mt][nt] = (f32x4){0.f,0.f,0.f,0.f};

  for (int chunk=0; chunk<2; chunk++){
    // ---- halo load: 324 pixels x 128 B contiguous each ----
    for (int i=0;i<11;i++){
      int task = t + 256*i;
      if (task < 2592){
        int q = task & 7, pix = task >> 3;
        int py = pix/18, px = pix - py*18;
        int gy = ty*16 - 1 + py, gx = tx*16 - 1 + px;
        uint4 v = make_uint4(0u,0u,0u,0u);
        if ((unsigned)gy < 256u && (unsigned)gx < 256u){
          int phh = gy>>3, pww = gx>>3, k = (gy&7)*8 + (gx&7);
          v = *(const uint4*)&y[(((size_t)(b*1024 + phh*32 + pww))*64 + k)*128
                                + chunk*64 + q*8];
        }
        int ad = (py*19+px)*68 + q*8;
        *(uint2*)&L[ad]     = make_uint2(v.x, v.y);
        *(uint2*)&L[ad + 4] = make_uint2(v.z, v.w);
      }
    }
    __syncthreads();

    // ---- dwconv pair + gelu gate -> A ----
    #pragma unroll
    for (int cg=0; cg<8; cg++){
      float d1[4] = {0.f,0.f,0.f,0.f};
      float d2[4] = {0.f,0.f,0.f,0.f};
      const float* w1p = wdw + (chunk*32 + cg*4)*9;
      const float* w2p = wdw + (64 + chunk*32 + cg*4)*9;
      #pragma unroll
      for (int dy=0; dy<3; dy++)
        #pragma unroll
        for (int dx=0; dx<3; dx++){
          int base = ((y_+dy)*19 + (x_+dx))*68;
          const uint2 a1 = *(const uint2*)&L[base + cg*4];
          const uint2 a2 = *(const uint2*)&L[base + 32 + cg*4];
          const float* wp1 = w1p + dy*3 + dx;
          const float* wp2 = w2p + dy*3 + dx;
          d1[0] = fmaf(wp1[0],  bf2f((u16)(a1.x & 0xFFFFu)), d1[0]);
          d1[1] = fmaf(wp1[9],  bf2f((u16)(a1.x >> 16)),     d1[1]);
          d1[2] = fmaf(wp1[18], bf2f((u16)(a1.y & 0xFFFFu)), d1[2]);
          d1[3] = fmaf(wp1[27], bf2f((u16)(a1.y >> 16)),     d1[3]);
          d2[0] = fmaf(wp2[0],  bf2f((u16)(a2.x & 0xFFFFu)), d2[0]);
          d2[1] = fmaf(wp2[9],  bf2f((u16)(a2.x >> 16)),     d2[1]);
          d2[2] = fmaf(wp2[18], bf2f((u16)(a2.y & 0xFFFFu)), d2[2]);
          d2[3] = fmaf(wp2[27], bf2f((u16)(a2.y >> 16)),     d2[3]);
        }
      float gg[4];
      #pragma unroll
      for (int l=0;l<4;l++){
        float g1 = d1[l];
        float g = 0.5f * g1 * (1.f + erff(g1 * 0.70710678118654752f));
        gg[l] = g * d2[l];
      }
      int pos = ((cg>>1) ^ sw)*8 + (cg&1)*4;
      *(uint2*)&A[t*32 + pos] =
          make_uint2(pk_bf16(gg[0], gg[1]), pk_bf16(gg[2], gg[3]));
    }
    __syncthreads();

    // ---- GEMM: acc += act[pix][k32] * w_out[och][k32] ----
    bf16x8 bfr[4];
    #pragma unroll
    for (int nt=0;nt<4;nt++)
      bfr[nt] = *(const bf16x8*)&wbo[(nt*16 + ln15)*64 + chunk*32 + quad*8];
    #pragma unroll
    for (int mt=0;mt<4;mt++){
      int px8 = wv*64 + mt*16 + ln15;
      int q2 = quad ^ ((px8&3) ^ ((px8>>2)&3));
      bf16x8 af = *(const bf16x8*)&A[px8*32 + q2*8];
      #pragma unroll
      for (int nt=0;nt<4;nt++)
        acc[mt][nt] = MFMA(af, bfr[nt], acc[mt][nt]);
    }
    __syncthreads();   // A reads done before next chunk overwrites L/A
  }

  // ---- epilogue: coalesced float4 stores ----
  #pragma unroll
  for (int mt=0;mt<4;mt++){
    int row = ty*16 + wv*4 + mt;
    #pragma unroll
    for (int nt=0;nt<4;nt++){
      int och = nt*16 + ln15;
      f32x4 v = acc[mt][nt];
      float4 o4 = make_float4(v.x, v.y, v.z, v.w);
      *(float4*)(out + (((size_t)(b*64 + och))*256 + row)*256 + tx*16 + quad*4) = o4;
    }
  }
}

extern "C" void kernel_launch(void* const* d_in, const int* in_sizes, int n_in,
                              void* d_out, int out_size, void* d_ws, size_t ws_size,
                              hipStream_t stream){
  const float* img   = (const float*)d_in[0];
  const float* evt   = (const float*)d_in[1];
  const float* w_img = (const float*)d_in[2];
  const float* w_evt = (const float*)d_in[3];
  const float* w_dw  = (const float*)d_in[4];
  const float* filt  = (const float*)d_in[5];
  const float* w_out = (const float*)d_in[6];
  float* out = (float*)d_out;

  u16* wbi = (u16*)d_ws;                          // 16 KB
  u16* wbe = (u16*)((char*)d_ws + 16384);         // 16 KB
  u16* wbo = (u16*)((char*)d_ws + 32768);         //  8 KB
  u16* y   = (u16*)((char*)d_ws + 65536);         // 67.1 MB bf16 intermediate

  k_prep<<<80, 256, 0, stream>>>(w_img, w_evt, w_out, wbi, wbe, wbo);
  k_front<<<2048, 256, 0, stream>>>(img, evt, wbi, wbe, filt, y);
  k_back<<<1024, 256, 0, stream>>>(y, w_dw, wbo, out);
}

// Round 5
// 292.932 us; speedup vs baseline: 1.0558x; 1.0558x over previous
//
#include <hip/hip_runtime.h>
#include <math.h>

typedef unsigned short u16;
typedef unsigned int   u32;

#define S2 0.70710678118654752440f

typedef float f32x4 __attribute__((ext_vector_type(4)));
typedef short bf16x8 __attribute__((ext_vector_type(8)));
typedef float f32x2 __attribute__((ext_vector_type(2)));
typedef __bf16 bf16x2 __attribute__((ext_vector_type(2)));
#define MFMA(a,b,c) __builtin_amdgcn_mfma_f32_16x16x32_bf16(a,b,c,0,0,0)

__device__ __forceinline__ float bf2f(u16 u){
  union { u32 i; float f; } v; v.i = ((u32)u) << 16; return v.f;
}
// native scalar f32 -> bf16 (RNE), 1 VALU op on gfx950
__device__ __forceinline__ u16 f2bf(float f){
  union { __bf16 b; u16 u; } v; v.b = (__bf16)f; return v.u;
}
// native packed f32x2 -> bf16x2 (RNE) via fptrunc <2 x float>, selects v_cvt_pk_bf16_f32
__device__ __forceinline__ u32 pk_bf16(float lo, float hi){
  f32x2 s; s.x = lo; s.y = hi;
  union { bf16x2 h; u32 u; } v;
  v.h = __builtin_convertvector(s, bf16x2);
  return v.u;
}

struct C2 { float r, i; };

__device__ __forceinline__ void fft8_fwd(C2* y){
  C2 a0 = {y[0].r+y[4].r, y[0].i+y[4].i};
  C2 a1 = {y[0].r-y[4].r, y[0].i-y[4].i};
  C2 a2 = {y[2].r+y[6].r, y[2].i+y[6].i};
  C2 a3 = {y[2].r-y[6].r, y[2].i-y[6].i};
  C2 b0 = {y[1].r+y[5].r, y[1].i+y[5].i};
  C2 b1 = {y[1].r-y[5].r, y[1].i-y[5].i};
  C2 b2 = {y[3].r+y[7].r, y[3].i+y[7].i};
  C2 b3 = {y[3].r-y[7].r, y[3].i-y[7].i};
  C2 E0 = {a0.r+a2.r, a0.i+a2.i};
  C2 E2 = {a0.r-a2.r, a0.i-a2.i};
  C2 E1 = {a1.r+a3.i, a1.i-a3.r};
  C2 E3 = {a1.r-a3.i, a1.i+a3.r};
  C2 O0 = {b0.r+b2.r, b0.i+b2.i};
  C2 O2 = {b0.r-b2.r, b0.i-b2.i};
  C2 O1 = {b1.r+b3.i, b1.i-b3.r};
  C2 O3 = {b1.r-b3.i, b1.i+b3.r};
  C2 t1 = {S2*(O1.r+O1.i), S2*(O1.i-O1.r)};
  C2 t2 = {O2.i, -O2.r};
  C2 t3 = {S2*(O3.i-O3.r), -S2*(O3.r+O3.i)};
  y[0].r=E0.r+O0.r; y[0].i=E0.i+O0.i;
  y[4].r=E0.r-O0.r; y[4].i=E0.i-O0.i;
  y[1].r=E1.r+t1.r; y[1].i=E1.i+t1.i;
  y[5].r=E1.r-t1.r; y[5].i=E1.i-t1.i;
  y[2].r=E2.r+t2.r; y[2].i=E2.i+t2.i;
  y[6].r=E2.r-t2.r; y[6].i=E2.i-t2.i;
  y[3].r=E3.r+t3.r; y[3].i=E3.i+t3.i;
  y[7].r=E3.r-t3.r; y[7].i=E3.i-t3.i;
}

__device__ __forceinline__ void fft8_inv(C2* z){
  C2 A0 = {z[0].r+z[4].r, z[0].i+z[4].i};
  C2 A1 = {z[1].r+z[5].r, z[1].i+z[5].i};
  C2 A2 = {z[2].r+z[6].r, z[2].i+z[6].i};
  C2 A3 = {z[3].r+z[7].r, z[3].i+z[7].i};
  C2 D0 = {z[0].r-z[4].r, z[0].i-z[4].i};
  C2 D1 = {z[1].r-z[5].r, z[1].i-z[5].i};
  C2 D2 = {z[2].r-z[6].r, z[2].i-z[6].i};
  C2 D3 = {z[3].r-z[7].r, z[3].i-z[7].i};
  C2 B0 = D0;
  C2 B1 = {S2*(D1.r-D1.i), S2*(D1.i+D1.r)};
  C2 B2 = {-D2.i, D2.r};
  C2 B3 = {-S2*(D3.r+D3.i), S2*(D3.r-D3.i)};
  z[0].r = A0.r+A1.r+A2.r+A3.r;           z[0].i = A0.i+A1.i+A2.i+A3.i;
  z[2].r = A0.r-A2.r-(A1.i-A3.i);         z[2].i = A0.i-A2.i+(A1.r-A3.r);
  z[4].r = A0.r-A1.r+A2.r-A3.r;           z[4].i = A0.i-A1.i+A2.i-A3.i;
  z[6].r = A0.r-A2.r+(A1.i-A3.i);         z[6].i = A0.i-A2.i-(A1.r-A3.r);
  z[1].r = B0.r+B1.r+B2.r+B3.r;           z[1].i = B0.i+B1.i+B2.i+B3.i;
  z[3].r = B0.r-B2.r-(B1.i-B3.i);         z[3].i = B0.i-B2.i+(B1.r-B3.r);
  z[5].r = B0.r-B1.r+B2.r-B3.r;           z[5].i = B0.i-B1.i+B2.i-B3.i;
  z[7].r = B0.r-B2.r+(B1.i-B3.i);         z[7].i = B0.i-B2.i-(B1.r-B3.r);
}

__device__ __forceinline__ void rfft8_row(float* x){
  float et0=x[0]+x[4], et1=x[0]-x[4], et2=x[2]+x[6], et3=x[2]-x[6];
  float ot0=x[1]+x[5], ot1=x[1]-x[5], ot2=x[3]+x[7], ot3=x[3]-x[7];
  float E0=et0+et2, E2=et0-et2;
  float O0=ot0+ot2, O2=ot0-ot2;
  float om=S2*(ot1-ot3), op=S2*(ot1+ot3);
  x[0]=E0+O0;  x[1]=E0-O0;
  x[2]=et1+om; x[3]=-et3-op;
  x[4]=E2;     x[5]=-O2;
  x[6]=et1-om; x[7]=et3-op;
}

__device__ __forceinline__ void irfft8_row(float f0, C2 R1, C2 R2, C2 R3, float f4, float* x){
  float A0  = f0+f4, B0v = f0-f4;
  float A1r = R1.r+R3.r, A1i = R1.i-R3.i;
  float A2  = 2.f*R2.r;
  float D1r = R1.r-R3.r, D1i = R1.i+R3.i;
  float B1r = S2*(D1r-D1i), B1i = S2*(D1i+D1r);
  float B2  = -2.f*R2.i;
  const float k = 1.f/64.f;
  x[0]=k*(A0 +A2+2.f*A1r); x[2]=k*(A0 -A2-2.f*A1i);
  x[4]=k*(A0 +A2-2.f*A1r); x[6]=k*(A0 -A2+2.f*A1i);
  x[1]=k*(B0v+B2+2.f*B1r); x[3]=k*(B0v-B2-2.f*B1i);
  x[5]=k*(B0v+B2-2.f*B1r); x[7]=k*(B0v-B2+2.f*B1i);
}

// ---------------- K_prep: fp32 weights -> bf16 ----------------
__global__ void k_prep(const float* __restrict__ wi, const float* __restrict__ we,
                       const float* __restrict__ wo,
                       u16* __restrict__ wbi, u16* __restrict__ wbe, u16* __restrict__ wbo){
  int i = blockIdx.x*256 + threadIdx.x;   // 20480
  if (i < 8192)        wbi[i]        = f2bf(wi[i]);
  else if (i < 16384)  wbe[i-8192]   = f2bf(we[i-8192]);
  else if (i < 20480)  wbo[i-16384]  = f2bf(wo[i-16384]);
}

// ---------------- K_front: 1x1 convs (MFMA) + patch FFT ----------------
// block = 2 horizontal patches (128 pixels), 256 threads
// y layout (bf16): [b][ph(32)][pw(32)][k=r*8+col (64)][c' (128)] where
// c' = (c&31)|((c&32)<<1)|((c&64)>>1)  (chunk-contiguous permutation for k_back)
// T14 split staging: img global loads issue right after the evt-GEMM barrier,
// consumed (LDS write) after pe's read_spec+rFFTs -> HBM latency hidden.
__global__ __launch_bounds__(256, 2)
void k_front(const float* __restrict__ img, const float* __restrict__ evt,
             const u16* __restrict__ wbi, const u16* __restrict__ wbe,
             const float* __restrict__ filt, u16* __restrict__ yout){
  __shared__ __align__(16) u16 s_a[8192];      // 16 KB  [pix(128)][c(64)] xor-swizzled
  __shared__ __align__(16) u16 s_spec[16384];  // 32 KB  [och(128)][pix(128)] swizzled / stage

  const int t   = threadIdx.x;
  const int bid = blockIdx.x;          // 2048 = b(4) * ph(32) * bx(16)
  const int b   = bid >> 9;
  const int ph  = (bid >> 4) & 31;
  const int bx  = bid & 15;
  const int wv   = t >> 6;
  const int quad = (t >> 4) & 3;
  const int ln15 = t & 15;
  const int pc   = t >> 7;             // fft patch (0/1)
  const int c    = t & 127;            // fft channel (original index)

  auto stage_load = [&](const float* src, float4* v){
    #pragma unroll
    for (int i=0;i<8;i++){
      int task = t + 256*i;
      int ci = task>>5, q = task&31;
      int r = q>>2, j = q&3;
      v[i] = *(const float4*)(src +
          (((size_t)(b*64+ci)*256 + ph*8 + r)*256 + bx*16 + j*4));
    }
  };
  auto stage_write = [&](const float4* v){
    #pragma unroll
    for (int i=0;i<8;i++){
      int task = t + 256*i;
      int ci = task>>5, q = task&31;
      int r = q>>2, j = q&3;
      int p0 = (j>>1)*64 + r*8 + (j&1)*4;
      int gbase = ci>>3, cl = ci&7;
      float vv[4] = {v[i].x, v[i].y, v[i].z, v[i].w};
      #pragma unroll
      for (int w=0;w<4;w++){
        int p = p0+w;
        int g = gbase ^ (p&7) ^ r;
        s_a[p*64 + g*8 + cl] = f2bf(vv[w]);
      }
    }
  };

  auto do_gemm = [&](const u16* __restrict__ wb){
    f32x4 acc[2][8];
    #pragma unroll
    for (int nt=0;nt<2;nt++)
      #pragma unroll
      for (int mt=0;mt<8;mt++)
        acc[nt][mt] = (f32x4){0.f,0.f,0.f,0.f};
    const int nb = wv*32;
    #pragma unroll
    for (int kk=0;kk<2;kk++){
      bf16x8 bf0 = *(const bf16x8*)&wb[(nb      + ln15)*64 + kk*32 + quad*8];
      bf16x8 bf1 = *(const bf16x8*)&wb[(nb + 16 + ln15)*64 + kk*32 + quad*8];
      #pragma unroll
      for (int mt=0;mt<8;mt++){
        int pix = mt*16 + ln15;
        int g = (kk*4+quad) ^ (pix&7) ^ ((pix>>3)&7);
        bf16x8 af = *(const bf16x8*)&s_a[pix*64 + g*8];
        acc[0][mt] = MFMA(af, bf0, acc[0][mt]);
        acc[1][mt] = MFMA(af, bf1, acc[1][mt]);
      }
    }
    #pragma unroll
    for (int nt=0;nt<2;nt++){
      int och = nb + nt*16 + ln15;
      #pragma unroll
      for (int mt=0;mt<8;mt++){
        int p0 = mt*16 + quad*4;
        f32x4 v = acc[nt][mt];
        u32 lo = pk_bf16(v.x, v.y);
        u32 hi = pk_bf16(v.z, v.w);
        int d = (p0>>3) ^ (och&7);
        u32* dst = (u32*)&s_spec[och*128 + d*8 + (p0&7)];
        dst[0] = lo; dst[1] = hi;
      }
    }
  };

  auto read_spec = [&](float* p){
    #pragma unroll
    for (int d=0; d<8; d++){
      int cz = (pc*8+d) ^ (c&7);
      const uint4 q4 = *(const uint4*)&s_spec[c*128 + cz*8];
      u32 ws4[4] = {q4.x, q4.y, q4.z, q4.w};
      #pragma unroll
      for (int e=0;e<4;e++){
        p[d*8+2*e]   = bf2f((u16)(ws4[e] & 0xFFFFu));
        p[d*8+2*e+1] = bf2f((u16)(ws4[e] >> 16));
      }
    }
  };

  // ---- event: stage -> GEMM -> row spectra ----
  {
    float4 sv[8];
    stage_load(evt, sv);
    stage_write(sv);
  }
  __syncthreads();
  do_gemm(wbe);
  __syncthreads();

  // ---- prefetch img into regs (hidden under pe read+FFT), then consume ----
  float4 sv[8];
  stage_load(img, sv);      // global loads in flight during pe phase

  float pe[64];
  read_spec(pe);
  #pragma unroll
  for (int r=0;r<8;r++) rfft8_row(&pe[r*8]);

  stage_write(sv);          // s_a free since the post-evt-GEMM barrier
  __syncthreads();          // covers: pe reads done + s_a img visible
  do_gemm(wbi);
  __syncthreads();

  // ---- FFT2: merged columns, X = (Fi+1)*(Fe*f) ----
  float pi[64];
  read_spec(pi);
  __syncthreads();          // all s_spec reads done; safe to overwrite below
  #pragma unroll
  for (int r=0;r<8;r++) rfft8_row(&pi[r*8]);

  C2 X[8][5];
  {
    const float* fl = filt + c*40;
    #pragma unroll
    for (int j=0;j<5;j++){
      C2 e8[8], i8[8];
      #pragma unroll
      for (int r=0;r<8;r++){
        float re_e, im_e, re_i, im_i;
        if (j==0){ re_e=pe[r*8];   im_e=0.f; re_i=pi[r*8];   im_i=0.f; }
        else if (j==4){ re_e=pe[r*8+1]; im_e=0.f; re_i=pi[r*8+1]; im_i=0.f; }
        else { re_e=pe[r*8+2*j]; im_e=pe[r*8+2*j+1];
               re_i=pi[r*8+2*j]; im_i=pi[r*8+2*j+1]; }
        e8[r].r=re_e; e8[r].i=im_e; i8[r].r=re_i; i8[r].i=im_i;
      }
      fft8_fwd(e8);
      fft8_fwd(i8);
      #pragma unroll
      for (int ky=0;ky<8;ky++){
        float f  = fl[ky*5+j];
        float fr = e8[ky].r*f, fi2 = e8[ky].i*f;
        X[ky][j].r = i8[ky].r*fr - i8[ky].i*fi2 + fr;
        X[ky][j].i = i8[ky].r*fi2 + i8[ky].i*fr + fi2;
      }
    }
    #pragma unroll
    for (int j=0;j<5;j++){
      C2 z[8];
      #pragma unroll
      for (int ky=0;ky<8;ky++) z[ky] = X[ky][j];
      fft8_inv(z);
      #pragma unroll
      for (int ky=0;ky<8;ky++) X[ky][j] = z[ky];
    }
  }

  // row irffts -> stage writes (channel-permuted)
  {
    const int cp = (c&31) | ((c&32)<<1) | ((c&64)>>1);
    #pragma unroll
    for (int r=0;r<8;r++){
      float xr[8];
      irfft8_row(X[r][0].r, X[r][1], X[r][2], X[r][3], X[r][4].r, xr);
      #pragma unroll
      for (int n2=0;n2<8;n2++)
        s_spec[(pc*64 + r*8 + n2)*128 + cp] = f2bf(xr[n2]);
    }
  }
  __syncthreads();

  // ---- coalesced store (32 KB) ----
  {
    const uint4* sg = (const uint4*)s_spec;
    uint4* dst = (uint4*)(yout + (size_t)(b*1024 + ph*32 + bx*2)*8192);
    #pragma unroll
    for (int i=0;i<8;i++){
      int q2 = t + 256*i;
      dst[q2] = sg[q2];
    }
  }
}

// ---------------- K_back: dw3x3 + gelu-gate + 1x1 out (MFMA) ----------------
// block = 16x16 pixel tile, 256 threads. Reads permuted y: chunk ch = 128 B contiguous.
// T14 split halo: chunk-1 loads issue during chunk-0 dwconv; LDS write after gemm0.
__global__ __launch_bounds__(256, 2)
void k_back(const u16* __restrict__ y, const float* __restrict__ wdw,
            const u16* __restrict__ wbo, float* __restrict__ out){
  __shared__ __align__(16) u16 L[18*19*68];   // 46512 B: [py 18][px 19][ch 64 +4 pad]
  __shared__ __align__(16) u16 A[256*32];     // 16384 B: [pix 256][ch 32] xor-swizzled

  const int t   = threadIdx.x;
  const int bid = blockIdx.x;     // 1024 = b(4) * ty(16) * tx(16)
  const int b   = bid >> 8;
  const int ty  = (bid >> 4) & 15;
  const int tx  = bid & 15;
  const int wv   = t >> 6;
  const int quad = (t >> 4) & 3;
  const int ln15 = t & 15;
  const int y_  = t >> 4, x_ = t & 15;
  const int sw  = (t&3) ^ ((t>>2)&3);

  auto halo_load = [&](int chunk, uint4* hv){
    #pragma unroll
    for (int i=0;i<11;i++){
      int task = t + 256*i;
      uint4 v = make_uint4(0u,0u,0u,0u);
      if (task < 2592){
        int q = task & 7, pix = task >> 3;
        int py = pix/18, px = pix - py*18;
        int gy = ty*16 - 1 + py, gx = tx*16 - 1 + px;
        if ((unsigned)gy < 256u && (unsigned)gx < 256u){
          int phh = gy>>3, pww = gx>>3, k = (gy&7)*8 + (gx&7);
          v = *(const uint4*)&y[(((size_t)(b*1024 + phh*32 + pww))*64 + k)*128
                                + chunk*64 + q*8];
        }
      }
      hv[i] = v;
    }
  };
  auto halo_write = [&](const uint4* hv){
    #pragma unroll
    for (int i=0;i<11;i++){
      int task = t + 256*i;
      if (task < 2592){
        int q = task & 7, pix = task >> 3;
        int py = pix/18, px = pix - py*18;
        int ad = (py*19+px)*68 + q*8;
        *(uint2*)&L[ad]     = make_uint2(hv[i].x, hv[i].y);
        *(uint2*)&L[ad + 4] = make_uint2(hv[i].z, hv[i].w);
      }
    }
  };

  auto dwconv = [&](int chunk){
    #pragma unroll
    for (int cg=0; cg<8; cg++){
      float d1[4] = {0.f,0.f,0.f,0.f};
      float d2[4] = {0.f,0.f,0.f,0.f};
      const float* w1p = wdw + (chunk*32 + cg*4)*9;
      const float* w2p = wdw + (64 + chunk*32 + cg*4)*9;
      #pragma unroll
      for (int dy=0; dy<3; dy++)
        #pragma unroll
        for (int dx=0; dx<3; dx++){
          int base = ((y_+dy)*19 + (x_+dx))*68;
          const uint2 a1 = *(const uint2*)&L[base + cg*4];
          const uint2 a2 = *(const uint2*)&L[base + 32 + cg*4];
          const float* wp1 = w1p + dy*3 + dx;
          const float* wp2 = w2p + dy*3 + dx;
          d1[0] = fmaf(wp1[0],  bf2f((u16)(a1.x & 0xFFFFu)), d1[0]);
          d1[1] = fmaf(wp1[9],  bf2f((u16)(a1.x >> 16)),     d1[1]);
          d1[2] = fmaf(wp1[18], bf2f((u16)(a1.y & 0xFFFFu)), d1[2]);
          d1[3] = fmaf(wp1[27], bf2f((u16)(a1.y >> 16)),     d1[3]);
          d2[0] = fmaf(wp2[0],  bf2f((u16)(a2.x & 0xFFFFu)), d2[0]);
          d2[1] = fmaf(wp2[9],  bf2f((u16)(a2.x >> 16)),     d2[1]);
          d2[2] = fmaf(wp2[18], bf2f((u16)(a2.y & 0xFFFFu)), d2[2]);
          d2[3] = fmaf(wp2[27], bf2f((u16)(a2.y >> 16)),     d2[3]);
        }
      float gg[4];
      #pragma unroll
      for (int l=0;l<4;l++){
        // tanh-form GELU (max dev vs exact erf-GELU ~3e-3; absmax headroom 7+)
        float g1 = d1[l];
        float u  = 0.7978845608028654f * fmaf(0.044715f*g1*g1, g1, g1);
        float e  = __expf(2.f*u);
        float th = 1.f - 2.f*__builtin_amdgcn_rcpf(e + 1.f);
        float g  = 0.5f * g1 * (1.f + th);
        gg[l] = g * d2[l];
      }
      int pos = ((cg>>1) ^ sw)*8 + (cg&1)*4;
      *(uint2*)&A[t*32 + pos] =
          make_uint2(pk_bf16(gg[0], gg[1]), pk_bf16(gg[2], gg[3]));
    }
  };

  auto do_gemm = [&](int chunk, f32x4 (&acc)[4][4]){
    bf16x8 bfr[4];
    #pragma unroll
    for (int nt=0;nt<4;nt++)
      bfr[nt] = *(const bf16x8*)&wbo[(nt*16 + ln15)*64 + chunk*32 + quad*8];
    #pragma unroll
    for (int mt=0;mt<4;mt++){
      int px8 = wv*64 + mt*16 + ln15;
      int q2 = quad ^ ((px8&3) ^ ((px8>>2)&3));
      bf16x8 af = *(const bf16x8*)&A[px8*32 + q2*8];
      #pragma unroll
      for (int nt=0;nt<4;nt++)
        acc[mt][nt] = MFMA(af, bfr[nt], acc[mt][nt]);
    }
  };

  f32x4 acc[4][4];
  #pragma unroll
  for (int mt=0;mt<4;mt++)
    #pragma unroll
    for (int nt=0;nt<4;nt++)
      acc[mt][nt] = (f32x4){0.f,0.f,0.f,0.f};

  uint4 hv[11];
  // chunk 0 stage
  halo_load(0, hv);
  halo_write(hv);
  __syncthreads();            // L(ch0) visible

  // chunk 0 compute, chunk 1 loads in flight
  halo_load(1, hv);           // global loads hidden under dwconv0
  dwconv(0);
  __syncthreads();            // A(ch0) ready; all L(ch0) reads done
  do_gemm(0, acc);
  halo_write(hv);             // L(ch1) write concurrent with other waves' gemm0
  __syncthreads();            // L(ch1) visible; all A(ch0) reads done

  // chunk 1
  dwconv(1);
  __syncthreads();            // A(ch1) ready
  do_gemm(1, acc);

  // ---- epilogue: coalesced float4 stores ----
  #pragma unroll
  for (int mt=0;mt<4;mt++){
    int row = ty*16 + wv*4 + mt;
    #pragma unroll
    for (int nt=0;nt<4;nt++){
      int och = nt*16 + ln15;
      f32x4 v = acc[mt][nt];
      float4 o4 = make_float4(v.x, v.y, v.z, v.w);
      *(float4*)(out + (((size_t)(b*64 + och))*256 + row)*256 + tx*16 + quad*4) = o4;
    }
  }
}

extern "C" void kernel_launch(void* const* d_in, const int* in_sizes, int n_in,
                              void* d_out, int out_size, void* d_ws, size_t ws_size,
                              hipStream_t stream){
  const float* img   = (const float*)d_in[0];
  const float* evt   = (const float*)d_in[1];
  const float* w_img = (const float*)d_in[2];
  const float* w_evt = (const float*)d_in[3];
  const float* w_dw  = (const float*)d_in[4];
  const float* filt  = (const float*)d_in[5];
  const float* w_out = (const float*)d_in[6];
  float* out = (float*)d_out;

  u16* wbi = (u16*)d_ws;                          // 16 KB
  u16* wbe = (u16*)((char*)d_ws + 16384);         // 16 KB
  u16* wbo = (u16*)((char*)d_ws + 32768);         //  8 KB
  u16* y   = (u16*)((char*)d_ws + 65536);         // 67.1 MB bf16 intermediate

  k_prep<<<80, 256, 0, stream>>>(w_img, w_evt, w_out, wbi, wbe, wbo);
  k_front<<<2048, 256, 0, stream>>>(img, evt, wbi, wbe, filt, y);
  k_back<<<1024, 256, 0, stream>>>(y, w_dw, wbo, out);
}